// Round 7
// baseline (2213.743 us; speedup 1.0000x reference)
//
#include <hip/hip_runtime.h>
#include <hip/hip_bf16.h>

typedef __bf16 bf16_t;
typedef bf16_t bf16x8 __attribute__((ext_vector_type(8)));
typedef bf16_t bf16x4 __attribute__((ext_vector_type(4)));
typedef bf16_t bf16x2 __attribute__((ext_vector_type(2)));
typedef float f32x4 __attribute__((ext_vector_type(4)));
typedef float f32x2 __attribute__((ext_vector_type(2)));

// ---------------------------------------------------------------------------
// async global -> LDS, 16B per lane (wave-uniform LDS base, HW adds lane*16)
// ---------------------------------------------------------------------------
__device__ __forceinline__ void load_lds16(const bf16_t* g, bf16_t* l) {
  __builtin_amdgcn_global_load_lds(
      (const __attribute__((address_space(1))) unsigned int*)g,
      (__attribute__((address_space(3))) unsigned int*)l,
      16, 0, 0);
}

// ---------------------------------------------------------------------------
__global__ void conv_f32_bf16(const float* __restrict__ src,
                              bf16_t* __restrict__ dst, long n) {
  long i = ((long)blockIdx.x * blockDim.x + threadIdx.x) * 8;
  if (i + 7 >= n) return;
  float4 a = *(const float4*)(src + i);
  float4 b = *(const float4*)(src + i + 4);
  bf16x8 v;
  v[0] = (bf16_t)a.x; v[1] = (bf16_t)a.y; v[2] = (bf16_t)a.z; v[3] = (bf16_t)a.w;
  v[4] = (bf16_t)b.x; v[5] = (bf16_t)b.y; v[6] = (bf16_t)b.z; v[7] = (bf16_t)b.w;
  *(bf16x8*)(dst + i) = v;
}

__global__ void conv_bf16_f32(const bf16_t* __restrict__ src,
                              float* __restrict__ dst, long n) {
  long i = (long)blockIdx.x * blockDim.x + threadIdx.x;
  if (i >= n) return;
  dst[i] = (float)src[i];
}

__global__ void transpose_conv(const float* __restrict__ src,
                               bf16_t* __restrict__ dst, int Ksrc, int Nsrc) {
  __shared__ float tile[32][33];
  int n0 = blockIdx.x * 32, k0 = blockIdx.y * 32;
  int tx = threadIdx.x, ty = threadIdx.y;  // (32, 8)
#pragma unroll
  for (int i = 0; i < 32; i += 8)
    tile[ty + i][tx] = src[(long)(k0 + ty + i) * Nsrc + n0 + tx];
  __syncthreads();
#pragma unroll
  for (int i = 0; i < 32; i += 8)
    dst[(long)(n0 + ty + i) * Ksrc + k0 + tx] = (bf16_t)tile[tx][ty + i];
}

// ---------------------------------------------------------------------------
// m97-style GEMM: D[M,N] = A[M,K] @ Bt[N,K]^T + bias
// ---------------------------------------------------------------------------
template <int STORE_MODE>
__global__ __launch_bounds__(256) void gemm_bt_128(
    const bf16_t* __restrict__ A, const bf16_t* __restrict__ Bt,
    const float* __restrict__ bias, void* __restrict__ Dout,
    int M, int N, int K) {
  __shared__ bf16_t As[128 * 32];
  __shared__ bf16_t Bs[128 * 32];
  const int tid = threadIdx.x;
  const int lane = tid & 63;
  const int w = tid >> 6;
  const int wr = w >> 1, wc = w & 1;
  const int m0 = blockIdx.y * 128, n0 = blockIdx.x * 128;

  f32x4 acc[4][4] = {};

  const int r0 = tid >> 2;
  const int kk = (tid & 3) * 8;
  const int fr = lane & 15;
  const int fk = (lane >> 4) * 8;

  for (int k0 = 0; k0 < K; k0 += 32) {
    load_lds16(A + (long)(m0 + r0) * K + k0 + kk, As + w * 512);
    load_lds16(A + (long)(m0 + 64 + r0) * K + k0 + kk, As + 2048 + w * 512);
    load_lds16(Bt + (long)(n0 + r0) * K + k0 + kk, Bs + w * 512);
    load_lds16(Bt + (long)(n0 + 64 + r0) * K + k0 + kk, Bs + 2048 + w * 512);
    asm volatile("s_waitcnt vmcnt(0)" ::: "memory");
    __syncthreads();

    bf16x8 af[4], bfx[4];
#pragma unroll
    for (int m = 0; m < 4; ++m)
      af[m] = *(const bf16x8*)&As[(wr * 64 + m * 16 + fr) * 32 + fk];
#pragma unroll
    for (int n = 0; n < 4; ++n)
      bfx[n] = *(const bf16x8*)&Bs[(wc * 64 + n * 16 + fr) * 32 + fk];
#pragma unroll
    for (int m = 0; m < 4; ++m)
#pragma unroll
      for (int n = 0; n < 4; ++n)
        acc[m][n] = __builtin_amdgcn_mfma_f32_16x16x32_bf16(af[m], bfx[n],
                                                            acc[m][n], 0, 0, 0);
    __syncthreads();
  }

  const int fq = lane >> 4;
#pragma unroll
  for (int m = 0; m < 4; ++m) {
#pragma unroll
    for (int n = 0; n < 4; ++n) {
      int col = n0 + wc * 64 + n * 16 + fr;
      float bv = bias[col];
#pragma unroll
      for (int r = 0; r < 4; ++r) {
        int row = m0 + wr * 64 + m * 16 + fq * 4 + r;
        float v = acc[m][n][r] + bv;
        if (STORE_MODE == 0)
          ((float*)Dout)[(long)row * N + col] = v;
        else
          ((bf16_t*)Dout)[(long)row * N + col] = (bf16_t)v;
      }
    }
  }
}

// ---------------------------------------------------------------------------
// Persistent recurrence, fence-free, TWO interleaved row-chains per WG.
// 128 rows = 8 independent 16-row groups (row r of h_t depends only on row r
// of h_{t-1}).  WG gid: p=gid&3, i=gid>>2 -> owns col tile [i*32, i*32+32) for
// groups g=p and g=p+4 (chains A/B).  Both chains share the SAME W slice
// (32 cols x 2048 K = 128 KB) staged once in LDS.
// Phases alternate A,B each t: chain X's handoff latency (store drain + flag
// propagation + poll + L3 fill, ~2 us) is hidden behind chain Y's phase.
// Wave w owns K-slab w*512.  Poll: wave 0 only, one flag per lane (64 = whole
// group), then barrier.  h stores sc0sc1 (write-through, no L2 allocation);
// A-loads sc0 (L2-cacheable; addresses are final once flagged); Z prefetch
// sc0sc1 (never L2-allocates a pre-store line).  gid%4 sets -> XCD pair
// {p, p+4} under round-robin dispatch (locality only).
// ---------------------------------------------------------------------------
__global__ __launch_bounds__(256, 1) void rnn_persistent5(
    const bf16_t* __restrict__ h0,
    bf16_t* __restrict__ Hbuf,        // Z in, h out, (T,B,H) bf16
    const bf16_t* __restrict__ WhhT,  // (2048 cols, 2048 K) bf16
    unsigned int* __restrict__ flags) {  // 512 flags, 64B apart, pre-zeroed
  __shared__ bf16_t Wlds[65536];      // 128 KB: elem ((k>>3)*32+col)*8 + (k&7)
  __shared__ float sred[4][16 * 36];  // 9.2 KB, padded stride 36

  const int tid = threadIdx.x, lane = tid & 63, w = tid >> 6;
  const int gid = blockIdx.x;
  const int p = gid & 3;              // group pair selector (XCDs p, p+4)
  const int i = gid >> 2;             // col tile 0..63
  const int n0 = i * 32;
  const int H = 2048;
  const long BH = 128L * 2048;
  const int kb = w * 512;             // wave K-slab
  const int fr = lane & 15, fg = lane >> 4;
  const int w64 = w * 64;

  // ---- stage W cols [n0, n0+32) into LDS (once) ----
  {
    const int scol = tid >> 3;          // 0..31
    const int sk = (tid & 7) * 8;       // k offset in 64-chunk
    const bf16_t* gsrc = WhhT + (long)(n0 + scol) * H + sk;
#pragma unroll 4
    for (int j = 0; j < 32; ++j) {
      bf16x8 v = *(const bf16x8*)(gsrc + j * 64);
      int k8 = j * 8 + (tid & 7);
      *(bf16x8*)&Wlds[(k8 * 32 + scol) * 8] = v;
    }
  }
  __syncthreads();

  // epilogue ownership: 2 contiguous cols per thread (16x32 tile = 512)
  const int jj = tid * 2;
  const int zrow = jj >> 5, zcol = jj & 31;
  const int sidx = zrow * 36 + zcol;

  for (int t = 0; t < 256; ++t) {
    const bf16_t* hp = (t == 0) ? h0 : Hbuf + (long)(t - 1) * BH;
    bf16_t* z = Hbuf + (long)t * BH;

#pragma unroll
    for (int c = 0; c < 2; ++c) {
      const int g = p + c * 4;          // this chain's row group
      const int m0 = g * 16;
      const long zoff = (long)(m0 + zrow) * H + n0 + zcol;

      // Z prefetch: sc0 sc1 (no L2 allocation of not-yet-final lines)
      float zvr;
      {
        const bf16_t* zp = z + zoff;
        asm volatile("global_load_dword %0, %1, off sc0 sc1"
                     : "=v"(zvr)
                     : "v"(zp)
                     : "memory");
      }

      // poll: wave 0 only, lane l watches producer tile l of group g
      if (t > 0 && w == 0) {
        const unsigned int* pf = flags + (((g << 6) | lane) << 4);
        unsigned int v;
        do {
          v = __hip_atomic_load(pf, __ATOMIC_RELAXED,
                                __HIP_MEMORY_SCOPE_AGENT);
          if (__all(v >= (unsigned int)t)) break;
          __builtin_amdgcn_s_sleep(1);
        } while (true);
      }
      __syncthreads();

      // ---- A-frags: 16 rows (fr) x K-slab 512, sc0 (L2-cacheable) ----
      const bf16_t* Ab = hp + (long)(m0 + fr) * H + kb + fg * 8;
      f32x4 a0, a1, a2, a3, a4, a5, a6, a7, a8, a9, a10, a11, a12, a13, a14,
          a15;
      asm volatile(
          "global_load_dwordx4 %0, %16, off sc0\n\t"
          "global_load_dwordx4 %1, %16, off offset:64 sc0\n\t"
          "global_load_dwordx4 %2, %16, off offset:128 sc0\n\t"
          "global_load_dwordx4 %3, %16, off offset:192 sc0\n\t"
          "global_load_dwordx4 %4, %16, off offset:256 sc0\n\t"
          "global_load_dwordx4 %5, %16, off offset:320 sc0\n\t"
          "global_load_dwordx4 %6, %16, off offset:384 sc0\n\t"
          "global_load_dwordx4 %7, %16, off offset:448 sc0\n\t"
          "global_load_dwordx4 %8, %16, off offset:512 sc0\n\t"
          "global_load_dwordx4 %9, %16, off offset:576 sc0\n\t"
          "global_load_dwordx4 %10, %16, off offset:640 sc0\n\t"
          "global_load_dwordx4 %11, %16, off offset:704 sc0\n\t"
          "global_load_dwordx4 %12, %16, off offset:768 sc0\n\t"
          "global_load_dwordx4 %13, %16, off offset:832 sc0\n\t"
          "global_load_dwordx4 %14, %16, off offset:896 sc0\n\t"
          "global_load_dwordx4 %15, %16, off offset:960 sc0\n\t"
          "s_waitcnt vmcnt(0)"
          : "=&v"(a0), "=&v"(a1), "=&v"(a2), "=&v"(a3), "=&v"(a4), "=&v"(a5),
            "=&v"(a6), "=&v"(a7), "=&v"(a8), "=&v"(a9), "=&v"(a10),
            "=&v"(a11), "=&v"(a12), "=&v"(a13), "=&v"(a14), "=&v"(a15)
          : "v"(Ab)
          : "memory");
      __builtin_amdgcn_sched_barrier(0);  // keep MFMA after the wait

      f32x4 acc0 = {}, acc1 = {};
#define STEPX(ks, A)                                                          \
  {                                                                           \
    bf16x8 w0 = *(const bf16x8*)&Wlds[((w64 + (ks) * 4 + fg) * 32 + fr) * 8]; \
    bf16x8 w1 =                                                               \
        *(const bf16x8*)&Wlds[((w64 + (ks) * 4 + fg) * 32 + 16 + fr) * 8];    \
    bf16x8 av = __builtin_bit_cast(bf16x8, A);                                \
    acc0 = __builtin_amdgcn_mfma_f32_16x16x32_bf16(av, w0, acc0, 0, 0, 0);    \
    acc1 = __builtin_amdgcn_mfma_f32_16x16x32_bf16(av, w1, acc1, 0, 0, 0);    \
  }
      STEPX(0, a0)   STEPX(1, a1)   STEPX(2, a2)   STEPX(3, a3)
      STEPX(4, a4)   STEPX(5, a5)   STEPX(6, a6)   STEPX(7, a7)
      STEPX(8, a8)   STEPX(9, a9)   STEPX(10, a10) STEPX(11, a11)
      STEPX(12, a12) STEPX(13, a13) STEPX(14, a14) STEPX(15, a15)
#undef STEPX

      // ---- cross-wave K-reduction (padded stride 36) ----
#pragma unroll
      for (int rr = 0; rr < 4; ++rr) {
        sred[w][(fg * 4 + rr) * 36 + fr] = acc0[rr];
        sred[w][(fg * 4 + rr) * 36 + 16 + fr] = acc1[rr];
      }
      __syncthreads();

      // ---- reduce 4 waves + Z + relu; sc0sc1 4B store ----
      f32x2 r = *(const f32x2*)&sred[0][sidx];
      {
        f32x2 r1 = *(const f32x2*)&sred[1][sidx];
        f32x2 r2 = *(const f32x2*)&sred[2][sidx];
        f32x2 r3 = *(const f32x2*)&sred[3][sidx];
        r = r + r1 + r2 + r3;
      }
      bf16x2 zv = __builtin_bit_cast(bf16x2, zvr);
      bf16x2 o;
#pragma unroll
      for (int c2 = 0; c2 < 2; ++c2) {
        float v = r[c2] + (float)zv[c2];
        o[c2] = (bf16_t)(v > 0.f ? v : 0.f);
      }
      {
        float ov = __builtin_bit_cast(float, o);
        const bf16_t* zp = z + zoff;
        asm volatile("global_store_dword %0, %1, off sc0 sc1" ::"v"(zp),
                     "v"(ov)
                     : "memory");
      }
      asm volatile("s_waitcnt vmcnt(0)" ::: "memory");
      __syncthreads();  // all threads' stores drained; sred WAR-safe
      if (tid == 0)
        __hip_atomic_store(flags + (((g << 6) | i) << 4),
                           (unsigned int)(t + 1), __ATOMIC_RELAXED,
                           __HIP_MEMORY_SCOPE_AGENT);
    }
  }
}

// ---------------------------------------------------------------------------
extern "C" void kernel_launch(void* const* d_in, const int* in_sizes, int n_in,
                              void* d_out, int out_size, void* d_ws,
                              size_t ws_size, hipStream_t stream) {
  const float* x   = (const float*)d_in[0];  // (T,B,D)
  const float* h0  = (const float*)d_in[1];  // (B,H)
  const float* Wxh = (const float*)d_in[2];  // (D,H)
  const float* Whh = (const float*)d_in[3];  // (H,H)
  const float* bh  = (const float*)d_in[4];  // (H,)
  const float* Whq = (const float*)d_in[5];  // (H,Q)
  const float* bq  = (const float*)d_in[6];  // (Q,)
  float* out = (float*)d_out;

  const int T = 256, B = 128, D = 1024, H = 2048, Q = 1024;
  const long MB = (long)T * B;  // 32768

  char* ws = (char*)d_ws;
  unsigned int* flags = (unsigned int*)ws;  ws += 512 * 64;  // padded flags
  bf16_t* x_bf = (bf16_t*)ws;  ws += MB * D * 2;             // 64 MiB
  bf16_t* Hbuf = (bf16_t*)ws;  ws += MB * H * 2;             // 128 MiB (Z->h)
  bf16_t* h0bf = (bf16_t*)ws;  ws += (long)B * H * 2;
  bf16_t* WxhT = (bf16_t*)ws;  ws += (long)H * D * 2;
  bf16_t* WhhT = (bf16_t*)ws;  ws += (long)H * H * 2;
  bf16_t* WhqT = (bf16_t*)ws;  ws += (long)Q * H * 2;

  hipMemsetAsync(flags, 0, 512 * 64, stream);

  // --- convert inputs to bf16 (weights transposed to N x K) ---
  conv_f32_bf16<<<(int)(MB * D / 8 / 256), 256, 0, stream>>>(x, x_bf, MB * D);
  conv_f32_bf16<<<(int)((long)B * H / 8 / 256), 256, 0, stream>>>(h0, h0bf,
                                                                  (long)B * H);
  transpose_conv<<<dim3(H / 32, D / 32), dim3(32, 8), 0, stream>>>(Wxh, WxhT, D, H);
  transpose_conv<<<dim3(H / 32, H / 32), dim3(32, 8), 0, stream>>>(Whh, WhhT, H, H);
  transpose_conv<<<dim3(Q / 32, H / 32), dim3(32, 8), 0, stream>>>(Whq, WhqT, H, Q);

  // --- Z = x @ W_xh + b_h  (all timesteps), bf16 into Hbuf ---
  gemm_bt_128<1><<<dim3(H / 128, MB / 128), 256, 0, stream>>>(
      x_bf, WxhT, bh, Hbuf, (int)MB, H, D);

  // --- entire recurrence in ONE persistent kernel, 2 chains per WG ---
  rnn_persistent5<<<256, 256, 0, stream>>>(h0bf, Hbuf, WhhT, flags);

  // --- out = H @ W_hq + b_q  (fp32 straight to d_out) ---
  gemm_bt_128<0><<<dim3(Q / 128, MB / 128), 256, 0, stream>>>(
      Hbuf, WhqT, bq, out, (int)MB, Q, H);

  // --- final h (fp32) appended after (T*B, Q) block ---
  conv_bf16_f32<<<(int)((long)B * H / 256), 256, 0, stream>>>(
      Hbuf + (long)(T - 1) * B * H, out + MB * Q, (long)B * H);
}